// Round 1
// baseline (455.932 us; speedup 1.0000x reference)
//
#include <hip/hip_runtime.h>
#include <hip/hip_bf16.h>

typedef short bf16x8 __attribute__((ext_vector_type(8)));
typedef float f32x16 __attribute__((ext_vector_type(16)));

#define GN 8192
#define GD 128

// ws layout:
// [0, 32768)            : s (fp32, 8192)  = rsqrt(rowsum)
// [32768, +2359296)     : xs packed bf16: [128 kb][128 col][72 bf16] (64 valid k + 8 pad -> 144B row stride)
// [2392064, +16777216)  : partials fp32 [4][8192][128]

__global__ __launch_bounds__(256) void k_rowsum(const float* __restrict__ adj,
                                                float* __restrict__ s) {
  const int row = blockIdx.x;
  const float4* p = (const float4*)(adj + (size_t)row * GN);
  float acc = 0.f;
#pragma unroll
  for (int i = 0; i < 8; ++i) {
    float4 v = p[threadIdx.x + i * 256];
    acc += (v.x + v.y) + (v.z + v.w);
  }
#pragma unroll
  for (int off = 32; off > 0; off >>= 1) acc += __shfl_down(acc, off, 64);
  __shared__ float red[4];
  if ((threadIdx.x & 63) == 0) red[threadIdx.x >> 6] = acc;
  __syncthreads();
  if (threadIdx.x == 0) {
    float t = (red[0] + red[1]) + (red[2] + red[3]);
    s[row] = (t > 0.f) ? rsqrtf(t) : 0.f;
  }
}

// Build xsT packed: xsp[kb][c][kk] = bf16( s[kb*64+kk] * x[kb*64+kk][c] ), 72 bf16 stride
__global__ __launch_bounds__(256) void k_pack(const float* __restrict__ x,
                                              const float* __restrict__ s,
                                              __hip_bfloat16* __restrict__ xsp) {
  const int kb = blockIdx.x;
  const int t = threadIdx.x;
  __shared__ float tile[64][129];
  __shared__ float sv[64];
  if (t < 64) sv[t] = s[kb * 64 + t];
  __syncthreads();
  const float4* xp = (const float4*)(x + (size_t)kb * 64 * GD);
#pragma unroll
  for (int j = 0; j < 8; ++j) {
    int i = t + j * 256;
    int r = i >> 5, c4 = i & 31;
    float4 v = xp[i];
    float sc = sv[r];
    tile[r][c4 * 4 + 0] = v.x * sc;
    tile[r][c4 * 4 + 1] = v.y * sc;
    tile[r][c4 * 4 + 2] = v.z * sc;
    tile[r][c4 * 4 + 3] = v.w * sc;
  }
  __syncthreads();
  const int c = t >> 1, h = t & 1;
  __hip_bfloat16 buf[32];
#pragma unroll
  for (int kk = 0; kk < 32; ++kk) buf[kk] = __float2bfloat16(tile[h * 32 + kk][c]);
  __hip_bfloat16* op = xsp + (size_t)kb * (128 * 72) + c * 72 + h * 32;
#pragma unroll
  for (int j = 0; j < 4; ++j) ((uint4*)op)[j] = ((uint4*)buf)[j];
}

// Main GEMM: partials[ks] = adj[:, ks-slice] @ xs[ks-slice, :]
__global__ __launch_bounds__(256, 2) void k_gemm(const float* __restrict__ adj,
                                                 const __hip_bfloat16* __restrict__ xsp,
                                                 float* __restrict__ part) {
  __shared__ __align__(16) __hip_bfloat16 Asm[64 * 72];
  __shared__ __align__(16) __hip_bfloat16 Bsm[128 * 72];
  const int mb = blockIdx.x;   // 0..127  (64-row tile)
  const int ks = blockIdx.y;   // 0..3    (K split, 2048 each)
  const int t = threadIdx.x;
  const int lane = t & 63;
  const int wave = t >> 6;
  const int wm = wave >> 1, wn = wave & 1;   // 2x2 wave grid over (M,N)

  f32x16 acc0, acc1;
#pragma unroll
  for (int i = 0; i < 16; ++i) { acc0[i] = 0.f; acc1[i] = 0.f; }

  const int ar = t >> 2;             // A-stage: row 0..63
  const int acg = (t & 3) * 16;      // A-stage: 16-col group
  const float* arow = adj + (size_t)(mb * 64 + ar) * GN + (size_t)ks * 2048 + acg;
  const uint4* bsrc_base = (const uint4*)(xsp + (size_t)(ks * 32) * (128 * 72));

  const int a_lds_off = ar * 72 + acg;
  const int afrag_row = wm * 32 + (lane & 31);
  const int koff = (lane >> 5) * 8;
  const int bcol0 = wn * 64 + (lane & 31);

  for (int kt = 0; kt < 32; ++kt) {          // 32 iterations of BK=64
    // --- stage A tile (fp32 -> bf16) ---
    float v[16];
    const float4* s4 = (const float4*)(arow + (size_t)kt * 64);
#pragma unroll
    for (int j = 0; j < 4; ++j) {
      float4 q = s4[j];
      v[j * 4 + 0] = q.x; v[j * 4 + 1] = q.y; v[j * 4 + 2] = q.z; v[j * 4 + 3] = q.w;
    }
    {
      __hip_bfloat16 hb[16];
#pragma unroll
      for (int i = 0; i < 16; ++i) hb[i] = __float2bfloat16(v[i]);
      uint4* d = (uint4*)(Asm + a_lds_off);
      d[0] = ((uint4*)hb)[0];
      d[1] = ((uint4*)hb)[1];
    }
    // --- stage B tile: straight copy of pre-packed layout (18432 B) ---
    {
      const uint4* bsv = bsrc_base + (size_t)kt * 1152;
      uint4* bd = (uint4*)Bsm;
      for (int i = t; i < 1152; i += 256) bd[i] = bsv[i];
    }
    __syncthreads();
#pragma unroll
    for (int kk = 0; kk < 64; kk += 16) {
      bf16x8 af = *(const bf16x8*)(Asm + afrag_row * 72 + kk + koff);
      bf16x8 b0 = *(const bf16x8*)(Bsm + bcol0 * 72 + kk + koff);
      bf16x8 b1 = *(const bf16x8*)(Bsm + (bcol0 + 32) * 72 + kk + koff);
      acc0 = __builtin_amdgcn_mfma_f32_32x32x16_bf16(af, b0, acc0, 0, 0, 0);
      acc1 = __builtin_amdgcn_mfma_f32_32x32x16_bf16(af, b1, acc1, 0, 0, 0);
    }
    __syncthreads();
  }

  float* pb = part + (size_t)ks * GN * GD + (size_t)(mb * 64 + wm * 32) * GD + wn * 64;
#pragma unroll
  for (int reg = 0; reg < 16; ++reg) {
    int r = (reg & 3) + 8 * (reg >> 2) + 4 * (lane >> 5);
    int cc = lane & 31;
    pb[(size_t)r * GD + cc] = acc0[reg];
    pb[(size_t)r * GD + cc + 32] = acc1[reg];
  }
}

// Reduce split-K partials, scale by s_i, out = h @ W^T + b  (MFMA)
__global__ __launch_bounds__(256) void k_out(const float* __restrict__ part,
                                             const float* __restrict__ s,
                                             const float* __restrict__ W,
                                             const float* __restrict__ b,
                                             float* __restrict__ out) {
  __shared__ __align__(16) __hip_bfloat16 Hs[32 * 136];   // 272B row stride
  __shared__ __align__(16) __hip_bfloat16 Ws[128 * 136];
  __shared__ float bs[128];
  const int t = threadIdx.x;
  const int rowbase = blockIdx.x * 32;
  if (t < 128) bs[t] = b[t];
  // stage H = (sum of 4 partials) * s_row, bf16
#pragma unroll
  for (int j = 0; j < 4; ++j) {
    int i = t + j * 256;             // 0..1023 : 32 rows x 32 float4
    int r = i >> 5, c4 = i & 31;
    size_t idx = (size_t)(rowbase + r) * GD + c4 * 4;
    float4 p0 = *(const float4*)(part + idx);
    float4 p1 = *(const float4*)(part + idx + (size_t)GN * GD);
    float4 p2 = *(const float4*)(part + idx + (size_t)2 * GN * GD);
    float4 p3 = *(const float4*)(part + idx + (size_t)3 * GN * GD);
    float sc = s[rowbase + r];
    __hip_bfloat16 hb[4];
    hb[0] = __float2bfloat16((p0.x + p1.x + p2.x + p3.x) * sc);
    hb[1] = __float2bfloat16((p0.y + p1.y + p2.y + p3.y) * sc);
    hb[2] = __float2bfloat16((p0.z + p1.z + p2.z + p3.z) * sc);
    hb[3] = __float2bfloat16((p0.w + p1.w + p2.w + p3.w) * sc);
    *(uint2*)(Hs + r * 136 + c4 * 4) = *(uint2*)hb;
  }
  // stage W (row-major W[o][k] IS the B-operand layout for W^T)
#pragma unroll
  for (int j = 0; j < 16; ++j) {
    int i = t + j * 256;             // 0..4095 : 128 rows x 32 float4
    int o = i >> 5, k4 = i & 31;
    float4 w = *(const float4*)(W + (size_t)o * GD + k4 * 4);
    __hip_bfloat16 hb[4];
    hb[0] = __float2bfloat16(w.x);
    hb[1] = __float2bfloat16(w.y);
    hb[2] = __float2bfloat16(w.z);
    hb[3] = __float2bfloat16(w.w);
    *(uint2*)(Ws + o * 136 + k4 * 4) = *(uint2*)hb;
  }
  __syncthreads();
  const int lane = t & 63;
  const int wave = t >> 6;
  const int arow = lane & 31;
  const int koff = (lane >> 5) * 8;
  const int bcol = wave * 32 + (lane & 31);
  f32x16 acc;
#pragma unroll
  for (int i = 0; i < 16; ++i) acc[i] = 0.f;
#pragma unroll
  for (int kk = 0; kk < 128; kk += 16) {
    bf16x8 af = *(const bf16x8*)(Hs + arow * 136 + kk + koff);
    bf16x8 bf = *(const bf16x8*)(Ws + bcol * 136 + kk + koff);
    acc = __builtin_amdgcn_mfma_f32_32x32x16_bf16(af, bf, acc, 0, 0, 0);
  }
#pragma unroll
  for (int reg = 0; reg < 16; ++reg) {
    int r = (reg & 3) + 8 * (reg >> 2) + 4 * (lane >> 5);
    out[(size_t)(rowbase + r) * GD + bcol] = acc[reg] + bs[bcol];
  }
}

extern "C" void kernel_launch(void* const* d_in, const int* in_sizes, int n_in,
                              void* d_out, int out_size, void* d_ws, size_t ws_size,
                              hipStream_t stream) {
  const float* x   = (const float*)d_in[0];
  const float* adj = (const float*)d_in[1];
  const float* W   = (const float*)d_in[2];
  const float* b   = (const float*)d_in[3];
  float* out = (float*)d_out;

  float* s = (float*)d_ws;
  __hip_bfloat16* xsp = (__hip_bfloat16*)((char*)d_ws + 32768);
  float* part = (float*)((char*)d_ws + 32768 + 128 * 128 * 144);

  k_rowsum<<<8192, 256, 0, stream>>>(adj, s);
  k_pack<<<128, 256, 0, stream>>>(x, s, xsp);
  k_gemm<<<dim3(128, 4), 256, 0, stream>>>(adj, xsp, part);
  k_out<<<256, 256, 0, stream>>>(part, s, W, b, out);
}

// Round 2
// 414.095 us; speedup vs baseline: 1.1010x; 1.1010x over previous
//
#include <hip/hip_runtime.h>
#include <hip/hip_bf16.h>

typedef short bf16x8 __attribute__((ext_vector_type(8)));
typedef float f32x16 __attribute__((ext_vector_type(16)));
typedef float f32x4v __attribute__((ext_vector_type(4)));

#define GN 8192
#define GD 128
#define KSPLIT 8

// ws layout (16B-aligned offsets):
// [0, 32768)                  : s (fp32, 8192) = rsqrt(rowsum)
// [32768, +2359296)           : xs packed bf16: [128 kb][128 col][72 bf16]
// [2392064, +134217728)       : adj_bf16 row-major, pre-scaled by s_i  (128 MB)
// [136609792, +33554432)      : partials fp32 [8][8192][128]

// Pass 1: rowsum -> s_i, and rewrite row as bf16 * s_i.
// Non-temporal fp32 reads so the 256MB read stream doesn't evict the
// bf16 copy from L3 (we want pass 2 to hit L3).
__global__ __launch_bounds__(256) void k_rowcvt(const float* __restrict__ adj,
                                                float* __restrict__ s,
                                                __hip_bfloat16* __restrict__ adjb) {
  const int row = blockIdx.x;
  const int t = threadIdx.x;
  const f32x4v* p = (const f32x4v*)(adj + (size_t)row * GN);
  f32x4v v[8];
  float acc = 0.f;
#pragma unroll
  for (int i = 0; i < 8; ++i) {
    v[i] = __builtin_nontemporal_load(p + t + i * 256);
    acc += (v[i].x + v[i].y) + (v[i].z + v[i].w);
  }
#pragma unroll
  for (int off = 32; off > 0; off >>= 1) acc += __shfl_down(acc, off, 64);
  __shared__ float red[4];
  __shared__ float sbc;
  if ((t & 63) == 0) red[t >> 6] = acc;
  __syncthreads();
  if (t == 0) {
    float tot = (red[0] + red[1]) + (red[2] + red[3]);
    float sc = (tot > 0.f) ? rsqrtf(tot) : 0.f;
    sbc = sc;
    s[row] = sc;
  }
  __syncthreads();
  const float sc = sbc;
  __hip_bfloat16* orow = adjb + (size_t)row * GN;
#pragma unroll
  for (int i = 0; i < 8; ++i) {
    __hip_bfloat16 hb[4];
    hb[0] = __float2bfloat16(v[i].x * sc);
    hb[1] = __float2bfloat16(v[i].y * sc);
    hb[2] = __float2bfloat16(v[i].z * sc);
    hb[3] = __float2bfloat16(v[i].w * sc);
    *(uint2*)(orow + (size_t)(t + i * 256) * 4) = *(uint2*)hb;
  }
}

// Build xsT packed: xsp[kb][c][kk] = bf16( s[kb*64+kk] * x[kb*64+kk][c] ), 72 bf16 stride
__global__ __launch_bounds__(256) void k_pack(const float* __restrict__ x,
                                              const float* __restrict__ s,
                                              __hip_bfloat16* __restrict__ xsp) {
  const int kb = blockIdx.x;
  const int t = threadIdx.x;
  __shared__ float tile[64][129];
  __shared__ float sv[64];
  if (t < 64) sv[t] = s[kb * 64 + t];
  __syncthreads();
  const float4* xp = (const float4*)(x + (size_t)kb * 64 * GD);
#pragma unroll
  for (int j = 0; j < 8; ++j) {
    int i = t + j * 256;
    int r = i >> 5, c4 = i & 31;
    float4 v = xp[i];
    float sc = sv[r];
    tile[r][c4 * 4 + 0] = v.x * sc;
    tile[r][c4 * 4 + 1] = v.y * sc;
    tile[r][c4 * 4 + 2] = v.z * sc;
    tile[r][c4 * 4 + 3] = v.w * sc;
  }
  __syncthreads();
  const int c = t >> 1, h = t & 1;
  __hip_bfloat16 buf[32];
#pragma unroll
  for (int kk = 0; kk < 32; ++kk) buf[kk] = __float2bfloat16(tile[h * 32 + kk][c]);
  __hip_bfloat16* op = xsp + (size_t)kb * (128 * 72) + c * 72 + h * 32;
#pragma unroll
  for (int j = 0; j < 4; ++j) ((uint4*)op)[j] = ((uint4*)buf)[j];
}

// Main GEMM over bf16 A (pre-scaled): partials[ks] = adjb[:, slice] @ xs[slice, :]
__global__ __launch_bounds__(256, 4) void k_gemm(const __hip_bfloat16* __restrict__ adjb,
                                                 const __hip_bfloat16* __restrict__ xsp,
                                                 float* __restrict__ part) {
  __shared__ __align__(16) __hip_bfloat16 Asm[64 * 72];
  __shared__ __align__(16) __hip_bfloat16 Bsm[128 * 72];
  const int mb = blockIdx.x;   // 0..127  (64-row tile)
  const int ks = blockIdx.y;   // 0..7    (K split, 1024 each)
  const int t = threadIdx.x;
  const int lane = t & 63;
  const int wave = t >> 6;
  const int wm = wave >> 1, wn = wave & 1;

  f32x16 acc0, acc1;
#pragma unroll
  for (int i = 0; i < 16; ++i) { acc0[i] = 0.f; acc1[i] = 0.f; }

  const int ar = t >> 2;             // A-stage: row 0..63
  const int acg = (t & 3) * 16;      // A-stage: 16-elem (32B) col group
  const __hip_bfloat16* arow = adjb + (size_t)(mb * 64 + ar) * GN + ks * 1024 + acg;
  const uint4* bsrc_base = (const uint4*)(xsp + (size_t)(ks * 16) * (128 * 72));

  const int a_lds_off = ar * 72 + acg;
  const int afrag_row = wm * 32 + (lane & 31);
  const int koff = (lane >> 5) * 8;
  const int bcol0 = wn * 64 + (lane & 31);

  for (int kt = 0; kt < 16; ++kt) {          // 16 iterations of BK=64
    // --- stage A tile (already bf16, straight 32B/thread copy) ---
    {
      const uint4* s4 = (const uint4*)(arow + (size_t)kt * 64);
      uint4 q0 = s4[0];
      uint4 q1 = s4[1];
      uint4* d = (uint4*)(Asm + a_lds_off);
      d[0] = q0;
      d[1] = q1;
    }
    // --- stage B tile: straight copy of pre-packed layout (18432 B) ---
    {
      const uint4* bsv = bsrc_base + (size_t)kt * 1152;
      uint4* bd = (uint4*)Bsm;
      for (int i = t; i < 1152; i += 256) bd[i] = bsv[i];
    }
    __syncthreads();
#pragma unroll
    for (int kk = 0; kk < 64; kk += 16) {
      bf16x8 af = *(const bf16x8*)(Asm + afrag_row * 72 + kk + koff);
      bf16x8 b0 = *(const bf16x8*)(Bsm + bcol0 * 72 + kk + koff);
      bf16x8 b1 = *(const bf16x8*)(Bsm + (bcol0 + 32) * 72 + kk + koff);
      acc0 = __builtin_amdgcn_mfma_f32_32x32x16_bf16(af, b0, acc0, 0, 0, 0);
      acc1 = __builtin_amdgcn_mfma_f32_32x32x16_bf16(af, b1, acc1, 0, 0, 0);
    }
    __syncthreads();
  }

  float* pb = part + (size_t)ks * GN * GD + (size_t)(mb * 64 + wm * 32) * GD + wn * 64;
#pragma unroll
  for (int reg = 0; reg < 16; ++reg) {
    int r = (reg & 3) + 8 * (reg >> 2) + 4 * (lane >> 5);
    int cc = lane & 31;
    pb[(size_t)r * GD + cc] = acc0[reg];
    pb[(size_t)r * GD + cc + 32] = acc1[reg];
  }
}

// Reduce split-K partials (already fully scaled), out = h @ W^T + b  (MFMA)
__global__ __launch_bounds__(256) void k_out(const float* __restrict__ part,
                                             const float* __restrict__ W,
                                             const float* __restrict__ b,
                                             float* __restrict__ out) {
  __shared__ __align__(16) __hip_bfloat16 Hs[32 * 136];
  __shared__ __align__(16) __hip_bfloat16 Ws[128 * 136];
  __shared__ float bs[128];
  const int t = threadIdx.x;
  const int rowbase = blockIdx.x * 32;
  if (t < 128) bs[t] = b[t];
  // stage H = sum of 8 partials, bf16
#pragma unroll
  for (int j = 0; j < 4; ++j) {
    int i = t + j * 256;             // 0..1023 : 32 rows x 32 float4
    int r = i >> 5, c4 = i & 31;
    size_t idx = (size_t)(rowbase + r) * GD + c4 * 4;
    float4 a = {0.f, 0.f, 0.f, 0.f};
#pragma unroll
    for (int ksl = 0; ksl < KSPLIT; ++ksl) {
      float4 p = *(const float4*)(part + idx + (size_t)ksl * GN * GD);
      a.x += p.x; a.y += p.y; a.z += p.z; a.w += p.w;
    }
    __hip_bfloat16 hb[4];
    hb[0] = __float2bfloat16(a.x);
    hb[1] = __float2bfloat16(a.y);
    hb[2] = __float2bfloat16(a.z);
    hb[3] = __float2bfloat16(a.w);
    *(uint2*)(Hs + r * 136 + c4 * 4) = *(uint2*)hb;
  }
  // stage W (row-major W[o][k] IS the B-operand layout for W^T)
#pragma unroll
  for (int j = 0; j < 16; ++j) {
    int i = t + j * 256;             // 0..4095 : 128 rows x 32 float4
    int o = i >> 5, k4 = i & 31;
    float4 w = *(const float4*)(W + (size_t)o * GD + k4 * 4);
    __hip_bfloat16 hb[4];
    hb[0] = __float2bfloat16(w.x);
    hb[1] = __float2bfloat16(w.y);
    hb[2] = __float2bfloat16(w.z);
    hb[3] = __float2bfloat16(w.w);
    *(uint2*)(Ws + o * 136 + k4 * 4) = *(uint2*)hb;
  }
  __syncthreads();
  const int lane = t & 63;
  const int wave = t >> 6;
  const int arow = lane & 31;
  const int koff = (lane >> 5) * 8;
  const int bcol = wave * 32 + (lane & 31);
  f32x16 acc;
#pragma unroll
  for (int i = 0; i < 16; ++i) acc[i] = 0.f;
#pragma unroll
  for (int kk = 0; kk < 128; kk += 16) {
    bf16x8 af = *(const bf16x8*)(Hs + arow * 136 + kk + koff);
    bf16x8 bf = *(const bf16x8*)(Ws + bcol * 136 + kk + koff);
    acc = __builtin_amdgcn_mfma_f32_32x32x16_bf16(af, bf, acc, 0, 0, 0);
  }
#pragma unroll
  for (int reg = 0; reg < 16; ++reg) {
    int r = (reg & 3) + 8 * (reg >> 2) + 4 * (lane >> 5);
    out[(size_t)(rowbase + r) * GD + bcol] = acc[reg] + bs[bcol];
  }
}

extern "C" void kernel_launch(void* const* d_in, const int* in_sizes, int n_in,
                              void* d_out, int out_size, void* d_ws, size_t ws_size,
                              hipStream_t stream) {
  const float* x   = (const float*)d_in[0];
  const float* adj = (const float*)d_in[1];
  const float* W   = (const float*)d_in[2];
  const float* b   = (const float*)d_in[3];
  float* out = (float*)d_out;

  float* s = (float*)d_ws;
  __hip_bfloat16* xsp  = (__hip_bfloat16*)((char*)d_ws + 32768);
  __hip_bfloat16* adjb = (__hip_bfloat16*)((char*)d_ws + 2392064);
  float* part = (float*)((char*)d_ws + 136609792);

  k_rowcvt<<<8192, 256, 0, stream>>>(adj, s, adjb);
  k_pack<<<128, 256, 0, stream>>>(x, s, xsp);
  k_gemm<<<dim3(128, KSPLIT), 256, 0, stream>>>(adjb, xsp, part);
  k_out<<<256, 256, 0, stream>>>(part, W, b, out);
}

// Round 3
// 398.331 us; speedup vs baseline: 1.1446x; 1.0396x over previous
//
#include <hip/hip_runtime.h>
#include <hip/hip_bf16.h>

typedef short bf16x8 __attribute__((ext_vector_type(8)));
typedef float f32x16 __attribute__((ext_vector_type(16)));
typedef float f32x4v __attribute__((ext_vector_type(4)));

#define GN 8192
#define GD 128
#define KSPLIT 8

// ws layout (16B-aligned offsets):
// [0, 32768)                  : s (fp32, 8192) = rsqrt(rowsum)
// [32768, +2359296)           : xs packed bf16: [128 kb][128 col][72 bf16]
// [2392064, +134217728)       : adj_bf16 row-major, pre-scaled by s_i  (128 MB)
// [136609792, +33554432)      : partials fp32 [8][8192][128]

// Pass 1: rowsum -> s_i, and rewrite row as bf16 * s_i.
__global__ __launch_bounds__(256) void k_rowcvt(const float* __restrict__ adj,
                                                float* __restrict__ s,
                                                __hip_bfloat16* __restrict__ adjb) {
  const int row = blockIdx.x;
  const int t = threadIdx.x;
  const f32x4v* p = (const f32x4v*)(adj + (size_t)row * GN);
  f32x4v v[8];
  float acc = 0.f;
#pragma unroll
  for (int i = 0; i < 8; ++i) {
    v[i] = __builtin_nontemporal_load(p + t + i * 256);
    acc += (v[i].x + v[i].y) + (v[i].z + v[i].w);
  }
#pragma unroll
  for (int off = 32; off > 0; off >>= 1) acc += __shfl_down(acc, off, 64);
  __shared__ float red[4];
  __shared__ float sbc;
  if ((t & 63) == 0) red[t >> 6] = acc;
  __syncthreads();
  if (t == 0) {
    float tot = (red[0] + red[1]) + (red[2] + red[3]);
    float sc = (tot > 0.f) ? rsqrtf(tot) : 0.f;
    sbc = sc;
    s[row] = sc;
  }
  __syncthreads();
  const float sc = sbc;
  __hip_bfloat16* orow = adjb + (size_t)row * GN;
#pragma unroll
  for (int i = 0; i < 8; ++i) {
    __hip_bfloat16 hb[4];
    hb[0] = __float2bfloat16(v[i].x * sc);
    hb[1] = __float2bfloat16(v[i].y * sc);
    hb[2] = __float2bfloat16(v[i].z * sc);
    hb[3] = __float2bfloat16(v[i].w * sc);
    *(uint2*)(orow + (size_t)(t + i * 256) * 4) = *(uint2*)hb;
  }
}

// Build xsT packed: xsp[kb][c][kk] = bf16( s[kb*64+kk] * x[kb*64+kk][c] ), 72 bf16 stride
__global__ __launch_bounds__(256) void k_pack(const float* __restrict__ x,
                                              const float* __restrict__ s,
                                              __hip_bfloat16* __restrict__ xsp) {
  const int kb = blockIdx.x;
  const int t = threadIdx.x;
  __shared__ float tile[64][129];
  __shared__ float sv[64];
  if (t < 64) sv[t] = s[kb * 64 + t];
  __syncthreads();
  const float4* xp = (const float4*)(x + (size_t)kb * 64 * GD);
#pragma unroll
  for (int j = 0; j < 8; ++j) {
    int i = t + j * 256;
    int r = i >> 5, c4 = i & 31;
    float4 v = xp[i];
    float sc = sv[r];
    tile[r][c4 * 4 + 0] = v.x * sc;
    tile[r][c4 * 4 + 1] = v.y * sc;
    tile[r][c4 * 4 + 2] = v.z * sc;
    tile[r][c4 * 4 + 3] = v.w * sc;
  }
  __syncthreads();
  const int c = t >> 1, h = t & 1;
  __hip_bfloat16 buf[32];
#pragma unroll
  for (int kk = 0; kk < 32; ++kk) buf[kk] = __float2bfloat16(tile[h * 32 + kk][c]);
  __hip_bfloat16* op = xsp + (size_t)kb * (128 * 72) + c * 72 + h * 32;
#pragma unroll
  for (int j = 0; j < 4; ++j) ((uint4*)op)[j] = ((uint4*)buf)[j];
}

// Main GEMM over bf16 A (pre-scaled): partials[ks] = adjb[:, slice] @ xs[slice, :]
// BM=128 tile, 4 waves in 2x2, each wave 2x2 sub-tiles of 32x32.
__global__ __launch_bounds__(256, 2) void k_gemm(const __hip_bfloat16* __restrict__ adjb,
                                                 const __hip_bfloat16* __restrict__ xsp,
                                                 float* __restrict__ part) {
  __shared__ __align__(16) __hip_bfloat16 Asm[128 * 72];
  __shared__ __align__(16) __hip_bfloat16 Bsm[128 * 72];
  const int mb = blockIdx.x;   // 0..63  (128-row tile)
  const int ks = blockIdx.y;   // 0..7   (K split, 1024 each)
  const int t = threadIdx.x;
  const int lane = t & 63;
  const int wave = t >> 6;
  const int wm = wave >> 1, wn = wave & 1;

  f32x16 acc00, acc01, acc10, acc11;
#pragma unroll
  for (int i = 0; i < 16; ++i) {
    acc00[i] = 0.f; acc01[i] = 0.f; acc10[i] = 0.f; acc11[i] = 0.f;
  }

  const int ar = t >> 1;             // A-stage: row 0..127
  const int ah = (t & 1) * 32;       // A-stage: 32-elem (64B) k-half
  const __hip_bfloat16* arow = adjb + (size_t)(mb * 128 + ar) * GN + ks * 1024 + ah;
  const char* bsrc_base = (const char*)(xsp + (size_t)(ks * 16) * (128 * 72));

  const int a_lds_off = ar * 72 + ah;
  const int afrag_row = wm * 64 + (lane & 31);
  const int koff = (lane >> 5) * 8;
  const int bcol0 = wn * 64 + (lane & 31);

  for (int kt = 0; kt < 16; ++kt) {          // 16 iterations of BK=64
    // --- stage B tile: async DMA of pre-packed linear layout (18432 B) ---
    {
      const char* bg = bsrc_base + (size_t)kt * 18432;
#pragma unroll
      for (int c = 0; c < 5; ++c) {
        int chunk = wave + c * 4;
        if (chunk < 18) {
          __builtin_amdgcn_global_load_lds(
              (const __attribute__((address_space(1))) unsigned int*)(bg + chunk * 1024 + lane * 16),
              (__attribute__((address_space(3))) unsigned int*)((char*)Bsm + chunk * 1024),
              16, 0, 0);
        }
      }
    }
    // --- stage A tile (bf16, 64B/thread, padded rows) ---
    {
      const uint4* s4 = (const uint4*)(arow + (size_t)kt * 64);
      uint4 q0 = s4[0], q1 = s4[1], q2 = s4[2], q3 = s4[3];
      uint4* d = (uint4*)(Asm + a_lds_off);
      d[0] = q0; d[1] = q1; d[2] = q2; d[3] = q3;
    }
    __syncthreads();
#pragma unroll
    for (int kk = 0; kk < 64; kk += 16) {
      bf16x8 a0 = *(const bf16x8*)(Asm + afrag_row * 72 + kk + koff);
      bf16x8 a1 = *(const bf16x8*)(Asm + (afrag_row + 32) * 72 + kk + koff);
      bf16x8 b0 = *(const bf16x8*)(Bsm + bcol0 * 72 + kk + koff);
      bf16x8 b1 = *(const bf16x8*)(Bsm + (bcol0 + 32) * 72 + kk + koff);
      acc00 = __builtin_amdgcn_mfma_f32_32x32x16_bf16(a0, b0, acc00, 0, 0, 0);
      acc01 = __builtin_amdgcn_mfma_f32_32x32x16_bf16(a0, b1, acc01, 0, 0, 0);
      acc10 = __builtin_amdgcn_mfma_f32_32x32x16_bf16(a1, b0, acc10, 0, 0, 0);
      acc11 = __builtin_amdgcn_mfma_f32_32x32x16_bf16(a1, b1, acc11, 0, 0, 0);
    }
    __syncthreads();
  }

  float* pb = part + (size_t)ks * GN * GD + (size_t)(mb * 128) * GD;
#pragma unroll
  for (int reg = 0; reg < 16; ++reg) {
    int r0 = wm * 64 + (reg & 3) + 8 * (reg >> 2) + 4 * (lane >> 5);
    int c0 = wn * 64 + (lane & 31);
    pb[(size_t)r0 * GD + c0] = acc00[reg];
    pb[(size_t)r0 * GD + c0 + 32] = acc01[reg];
    pb[(size_t)(r0 + 32) * GD + c0] = acc10[reg];
    pb[(size_t)(r0 + 32) * GD + c0 + 32] = acc11[reg];
  }
}

// Reduce split-K partials (already fully scaled), out = h @ W^T + b  (MFMA)
__global__ __launch_bounds__(256) void k_out(const float* __restrict__ part,
                                             const float* __restrict__ W,
                                             const float* __restrict__ b,
                                             float* __restrict__ out) {
  __shared__ __align__(16) __hip_bfloat16 Hs[32 * 136];
  __shared__ __align__(16) __hip_bfloat16 Ws[128 * 136];
  __shared__ float bs[128];
  const int t = threadIdx.x;
  const int rowbase = blockIdx.x * 32;
  if (t < 128) bs[t] = b[t];
  // stage H = sum of 8 partials, bf16
#pragma unroll
  for (int j = 0; j < 4; ++j) {
    int i = t + j * 256;             // 0..1023 : 32 rows x 32 float4
    int r = i >> 5, c4 = i & 31;
    size_t idx = (size_t)(rowbase + r) * GD + c4 * 4;
    float4 a = {0.f, 0.f, 0.f, 0.f};
#pragma unroll
    for (int ksl = 0; ksl < KSPLIT; ++ksl) {
      float4 p = *(const float4*)(part + idx + (size_t)ksl * GN * GD);
      a.x += p.x; a.y += p.y; a.z += p.z; a.w += p.w;
    }
    __hip_bfloat16 hb[4];
    hb[0] = __float2bfloat16(a.x);
    hb[1] = __float2bfloat16(a.y);
    hb[2] = __float2bfloat16(a.z);
    hb[3] = __float2bfloat16(a.w);
    *(uint2*)(Hs + r * 136 + c4 * 4) = *(uint2*)hb;
  }
  // stage W (row-major W[o][k] IS the B-operand layout for W^T)
#pragma unroll
  for (int j = 0; j < 16; ++j) {
    int i = t + j * 256;             // 0..4095 : 128 rows x 32 float4
    int o = i >> 5, k4 = i & 31;
    float4 w = *(const float4*)(W + (size_t)o * GD + k4 * 4);
    __hip_bfloat16 hb[4];
    hb[0] = __float2bfloat16(w.x);
    hb[1] = __float2bfloat16(w.y);
    hb[2] = __float2bfloat16(w.z);
    hb[3] = __float2bfloat16(w.w);
    *(uint2*)(Ws + o * 136 + k4 * 4) = *(uint2*)hb;
  }
  __syncthreads();
  const int lane = t & 63;
  const int wave = t >> 6;
  const int arow = lane & 31;
  const int koff = (lane >> 5) * 8;
  const int bcol = wave * 32 + (lane & 31);
  f32x16 acc;
#pragma unroll
  for (int i = 0; i < 16; ++i) acc[i] = 0.f;
#pragma unroll
  for (int kk = 0; kk < 128; kk += 16) {
    bf16x8 af = *(const bf16x8*)(Hs + arow * 136 + kk + koff);
    bf16x8 bf = *(const bf16x8*)(Ws + bcol * 136 + kk + koff);
    acc = __builtin_amdgcn_mfma_f32_32x32x16_bf16(af, bf, acc, 0, 0, 0);
  }
#pragma unroll
  for (int reg = 0; reg < 16; ++reg) {
    int r = (reg & 3) + 8 * (reg >> 2) + 4 * (lane >> 5);
    out[(size_t)(rowbase + r) * GD + bcol] = acc[reg] + bs[bcol];
  }
}

extern "C" void kernel_launch(void* const* d_in, const int* in_sizes, int n_in,
                              void* d_out, int out_size, void* d_ws, size_t ws_size,
                              hipStream_t stream) {
  const float* x   = (const float*)d_in[0];
  const float* adj = (const float*)d_in[1];
  const float* W   = (const float*)d_in[2];
  const float* b   = (const float*)d_in[3];
  float* out = (float*)d_out;

  float* s = (float*)d_ws;
  __hip_bfloat16* xsp  = (__hip_bfloat16*)((char*)d_ws + 32768);
  __hip_bfloat16* adjb = (__hip_bfloat16*)((char*)d_ws + 2392064);
  float* part = (float*)((char*)d_ws + 136609792);

  k_rowcvt<<<8192, 256, 0, stream>>>(adj, s, adjb);
  k_pack<<<128, 256, 0, stream>>>(x, s, xsp);
  k_gemm<<<dim3(64, KSPLIT), 256, 0, stream>>>(adjb, xsp, part);
  k_out<<<256, 256, 0, stream>>>(part, W, b, out);
}